// Round 1
// baseline (377.103 us; speedup 1.0000x reference)
//
#include <hip/hip_runtime.h>
#include <hip/hip_bf16.h>

// SparseNoisyMoE: B=8192, IN=512, OUT=720, E=16, K=2, MOE_TEMP=1.0 (eval: no noise)
// Strategy: compute only the K=2 selected experts per row (8x less FLOPs than the
// reference's dense einsum), via expert-grouped gather-GEMM (fp32 round 1).

#define BATCH 8192
#define IND   512
#define OUTD  720
#define NEXP  16

// ---------------- gating ----------------
// 256 threads = 16 rows x 16 experts. Grid = B/16 = 512 blocks.
__global__ __launch_bounds__(256) void gate_kernel(
    const float* __restrict__ x, const float* __restrict__ Wg,
    const float* __restrict__ bg,
    int* __restrict__ counts, float* __restrict__ Psum, float* __restrict__ Dsum,
    float* __restrict__ gates, unsigned short* __restrict__ lists)
{
    __shared__ float sg[16][17];
    __shared__ float Ploc[16];
    __shared__ float Dloc[16];
    int tid = threadIdx.x;
    if (tid < 16) { Ploc[tid] = 0.f; Dloc[tid] = 0.f; }
    __syncthreads();

    int r   = tid >> 4;      // 0..15 row within block
    int e   = tid & 15;      // expert
    int row = blockIdx.x * 16 + r;

    const float4* x4 = (const float4*)(x + (size_t)row * IND);
    float acc = bg[e];
    #pragma unroll 8
    for (int i4 = 0; i4 < IND / 4; ++i4) {
        float4 xv = x4[i4];
        int ib = i4 * 4;
        acc += xv.x * Wg[(ib + 0) * NEXP + e];
        acc += xv.y * Wg[(ib + 1) * NEXP + e];
        acc += xv.z * Wg[(ib + 2) * NEXP + e];
        acc += xv.w * Wg[(ib + 3) * NEXP + e];
    }
    sg[r][e] = acc;   // MOE_TEMP == 1.0, no division needed
    __syncthreads();

    if (tid < 16) {
        int rr   = tid;
        int row2 = blockIdx.x * 16 + rr;
        // top-2 (ties -> lower index first, matching lax.top_k)
        float v0 = -1e30f, v1 = -1e30f; int i0 = 0, i1 = 0;
        #pragma unroll
        for (int ee = 0; ee < 16; ++ee) {
            float v = sg[rr][ee];
            if (v > v0)      { v1 = v0; i1 = i0; v0 = v; i0 = ee; }
            else if (v > v1) { v1 = v;  i1 = ee; }
        }
        // softmax over the two top values
        float e1 = expf(v1 - v0);
        float inv2 = 1.f / (1.f + e1);
        gates[row2 * 2 + 0] = inv2;
        gates[row2 * 2 + 1] = e1 * inv2;
        int p0 = atomicAdd(&counts[i0], 1);
        lists[i0 * BATCH + p0] = (unsigned short)((row2 << 1) | 0);
        int p1 = atomicAdd(&counts[i1], 1);
        lists[i1 * BATCH + p1] = (unsigned short)((row2 << 1) | 1);
        // full softmax for load-balance loss
        float s = 0.f;
        float pr[16];
        #pragma unroll
        for (int ee = 0; ee < 16; ++ee) { pr[ee] = expf(sg[rr][ee] - v0); s += pr[ee]; }
        float invs = 1.f / s;
        #pragma unroll
        for (int ee = 0; ee < 16; ++ee) atomicAdd(&Ploc[ee], pr[ee] * invs);
        atomicAdd(&Dloc[i0], 1.f);
    }
    __syncthreads();
    if (tid < 16) {
        atomicAdd(&Psum[tid], Ploc[tid]);
        atomicAdd(&Dsum[tid], Dloc[tid]);
    }
}

// ---------------- expert gather-GEMM ----------------
// BM=64 rows, BN=64 cols, BK=16. 256 threads, 4x4 micro-tile each.
// grid = (12 n-tiles, 128 row-tiles worst case, 16 experts); empty tiles exit.
__global__ __launch_bounds__(256) void moe_kernel(
    const float* __restrict__ x, const float* __restrict__ We,
    const float* __restrict__ be,
    const int* __restrict__ counts, const float* __restrict__ gates,
    const unsigned short* __restrict__ lists, float* __restrict__ out)
{
    int e = blockIdx.z;
    int n = counts[e];
    int r0 = blockIdx.y * 64;
    if (r0 >= n) return;
    int n0 = blockIdx.x * 64;

    __shared__ float sA[16][64];   // [k][row] transposed
    __shared__ float sB[16][64];   // [k][col]
    __shared__ int   srow[64];
    __shared__ float sgw[64];

    int tid = threadIdx.x;
    if (tid < 64) {
        int idx = r0 + tid;
        if (idx < n) {
            int ent = lists[e * BATCH + idx];
            int row = ent >> 1;
            srow[tid] = row;
            sgw[tid]  = gates[row * 2 + (ent & 1)];
        } else {
            srow[tid] = 0;
            sgw[tid]  = 0.f;
        }
    }
    __syncthreads();

    int tm = tid >> 4, tn = tid & 15;
    float acc[4][4] = {};

    const float* Be = We + (size_t)e * (IND * OUTD);

    // staging assignments
    int ar  = tid >> 2;          // 0..63 : A row
    int ac4 = tid & 3;           // 0..3  : A float4 col within BK
    int bk  = tid >> 4;          // 0..15 : B k-row
    int bc4 = tid & 15;          // 0..15 : B float4 col
    const float* aptr = x + (size_t)srow[ar] * IND + ac4 * 4;
    int gcol = n0 + bc4 * 4;
    bool bok = (gcol < OUTD);    // OUTD % 4 == 0, so full float4 valid when true

    for (int kt = 0; kt < IND / 16; ++kt) {
        float4 av = *(const float4*)(aptr + kt * 16);
        float4 bv = make_float4(0.f, 0.f, 0.f, 0.f);
        if (bok) bv = *(const float4*)(Be + (size_t)(kt * 16 + bk) * OUTD + gcol);
        __syncthreads();   // previous iteration's reads done before overwrite
        sA[ac4 * 4 + 0][ar] = av.x;
        sA[ac4 * 4 + 1][ar] = av.y;
        sA[ac4 * 4 + 2][ar] = av.z;
        sA[ac4 * 4 + 3][ar] = av.w;
        *(float4*)&sB[bk][bc4 * 4] = bv;
        __syncthreads();
        #pragma unroll
        for (int kk = 0; kk < 16; ++kk) {
            float4 a = *(const float4*)&sA[kk][tm * 4];
            float4 b = *(const float4*)&sB[kk][tn * 4];
            acc[0][0] += a.x * b.x; acc[0][1] += a.x * b.y; acc[0][2] += a.x * b.z; acc[0][3] += a.x * b.w;
            acc[1][0] += a.y * b.x; acc[1][1] += a.y * b.y; acc[1][2] += a.y * b.z; acc[1][3] += a.y * b.w;
            acc[2][0] += a.z * b.x; acc[2][1] += a.z * b.y; acc[2][2] += a.z * b.z; acc[2][3] += a.z * b.w;
            acc[3][0] += a.w * b.x; acc[3][1] += a.w * b.y; acc[3][2] += a.w * b.z; acc[3][3] += a.w * b.w;
        }
    }

    // epilogue: out[row] += g * (acc + be[e])
    #pragma unroll
    for (int i = 0; i < 4; ++i) {
        int lr = tm * 4 + i;
        if (r0 + lr < n) {
            int   row = srow[lr];
            float gw  = sgw[lr];
            #pragma unroll
            for (int j = 0; j < 4; ++j) {
                int col = n0 + tn * 4 + j;
                if (col < OUTD) {
                    atomicAdd(&out[(size_t)row * OUTD + col],
                              gw * (acc[i][j] + be[e * OUTD + col]));
                }
            }
        }
    }
}

// ---------------- load-balance loss ----------------
__global__ void loss_kernel(const float* __restrict__ Psum,
                            const float* __restrict__ Dsum,
                            float* __restrict__ out)
{
    if (threadIdx.x == 0) {
        float s = 0.f;
        #pragma unroll
        for (int e = 0; e < NEXP; ++e)
            s += (Dsum[e] / (float)BATCH) * (Psum[e] / (float)BATCH);
        out[(size_t)BATCH * OUTD] = s * (float)NEXP;
    }
}

extern "C" void kernel_launch(void* const* d_in, const int* in_sizes, int n_in,
                              void* d_out, int out_size, void* d_ws, size_t ws_size,
                              hipStream_t stream)
{
    const float* x  = (const float*)d_in[0];
    const float* Wg = (const float*)d_in[1];
    const float* bg = (const float*)d_in[2];
    const float* We = (const float*)d_in[3];
    const float* be = (const float*)d_in[4];
    float* out = (float*)d_out;

    char* ws = (char*)d_ws;
    int*   counts = (int*)ws;                 // 16 ints
    float* Psum   = (float*)(ws + 64);        // 16 floats
    float* Dsum   = (float*)(ws + 128);       // 16 floats
    float* gates  = (float*)(ws + 256);                         // B*2 floats (64 KB)
    unsigned short* lists = (unsigned short*)(ws + 256 + BATCH * 2 * sizeof(float)); // 16*B ushort (256 KB)

    hipMemsetAsync(ws, 0, 256, stream);
    hipMemsetAsync(d_out, 0, (size_t)out_size * sizeof(float), stream);

    gate_kernel<<<BATCH / 16, 256, 0, stream>>>(x, Wg, bg, counts, Psum, Dsum, gates, lists);

    dim3 grid((OUTD + 63) / 64, BATCH / 64, NEXP);
    moe_kernel<<<grid, 256, 0, stream>>>(x, We, be, counts, gates, lists, out);

    loss_kernel<<<1, 64, 0, stream>>>(Psum, Dsum, out);
}